// Round 7
// baseline (1334.188 us; speedup 1.0000x reference)
//
#include <hip/hip_runtime.h>
#include <math.h>

#define D 256

typedef short short8 __attribute__((ext_vector_type(8)));
typedef float f32x4 __attribute__((ext_vector_type(4)));
typedef float f32x2 __attribute__((ext_vector_type(2)));
typedef unsigned int u32x4 __attribute__((ext_vector_type(4)));

__device__ __forceinline__ float bf2f(unsigned int h) {
  return __uint_as_float(h << 16);
}
__device__ __forceinline__ unsigned short f2bf(float f) {
  unsigned int u = __float_as_uint(f);
  u += 0x7fffu + ((u >> 16) & 1u);
  return (unsigned short)(u >> 16);
}
__device__ __forceinline__ unsigned int packtrunc(float a, float b) {
  return (__float_as_uint(a) >> 16) | (__float_as_uint(b) & 0xffff0000u);
}
__device__ __forceinline__ unsigned int pk_fp8x4(float a, float b, float c, float d) {
  unsigned int r = 0;
  r = __builtin_amdgcn_cvt_pk_fp8_f32(a, b, r, false);
  r = __builtin_amdgcn_cvt_pk_fp8_f32(c, d, r, true);
  return r;
}
__device__ __forceinline__ void up_fp8x4(unsigned int x, float& a, float& b, float& c,
                                         float& d) {
  f32x2 lo = __builtin_amdgcn_cvt_pk_f32_fp8(x, false);
  f32x2 hi = __builtin_amdgcn_cvt_pk_f32_fp8(x, true);
  a = lo.x; b = lo.y; c = hi.x; d = hi.y;
}
// non-temporal (L1-bypass) 16B load via native ext-vector type
__device__ __forceinline__ u32x4 ntload4(const void* p) {
  return __builtin_nontemporal_load((const u32x4*)p);
}
// non-temporal 8B load of packed (col:int, norm:float)
__device__ __forceinline__ void ntload_cn(const void* p, int& col, float& wn) {
  long long v = __builtin_nontemporal_load((const long long*)p);
  col = (int)(v & 0xffffffffll);
  wn = __int_as_float((int)(v >> 32));
}

// ---------------- degree count ----------------
__global__ __launch_bounds__(256) void k_count(const int* __restrict__ row,
                                               int* __restrict__ cnt, int E) {
  int i = blockIdx.x * 256 + threadIdx.x;
  if (i < E) atomicAdd(&cnt[row[i]], 1);
}

// ---------------- 3-phase exclusive scan over Npad2 (multiple of 1024) ----------------
__global__ __launch_bounds__(256) void k_scan1(const int* __restrict__ cnt,
                                               int* __restrict__ bsum) {
  __shared__ int sw[4];
  int b = blockIdx.x, tid = threadIdx.x, lane = tid & 63, w = tid >> 6;
  int4 v = *(const int4*)(cnt + (size_t)b * 1024 + tid * 4);
  int s = v.x + v.y + v.z + v.w;
#pragma unroll
  for (int d = 32; d; d >>= 1) s += __shfl_xor(s, d, 64);
  if (lane == 0) sw[w] = s;
  __syncthreads();
  if (tid == 0) bsum[b] = sw[0] + sw[1] + sw[2] + sw[3];
}

__global__ __launch_bounds__(256) void k_scan2(int* __restrict__ bsum, int nb,
                                               int* __restrict__ offs_end) {
  __shared__ int sw[4];
  int tid = threadIdx.x, lane = tid & 63, w = tid >> 6;
  int v = (tid < nb) ? bsum[tid] : 0;
  int x = v;
#pragma unroll
  for (int d = 1; d < 64; d <<= 1) {
    int y = __shfl_up(x, d, 64);
    if (lane >= d) x += y;
  }
  if (lane == 63) sw[w] = x;
  __syncthreads();
  int woff = 0;
  for (int i = 0; i < w; ++i) woff += sw[i];
  int incl = woff + x;
  if (tid < nb) bsum[tid] = incl - v;
  if (tid == 0) *offs_end = sw[0] + sw[1] + sw[2] + sw[3];
}

__global__ __launch_bounds__(256) void k_scan3(const int* __restrict__ cnt,
                                               const int* __restrict__ bbase,
                                               int* __restrict__ offs,
                                               float* __restrict__ dinv) {
  __shared__ int sw[4];
  int b = blockIdx.x, tid = threadIdx.x, lane = tid & 63, w = tid >> 6;
  size_t base = (size_t)b * 1024 + tid * 4;
  int4 v = *(const int4*)(cnt + base);
  int s = v.x + v.y + v.z + v.w;
  int x = s;
#pragma unroll
  for (int d = 1; d < 64; d <<= 1) {
    int y = __shfl_up(x, d, 64);
    if (lane >= d) x += y;
  }
  if (lane == 63) sw[w] = x;
  __syncthreads();
  int woff = bbase[b];
  for (int i = 0; i < w; ++i) woff += sw[i];
  int excl = woff + x - s;
  int4 o;
  o.x = excl;
  o.y = excl + v.x;
  o.z = o.y + v.y;
  o.w = o.z + v.z;
  *(int4*)(offs + base) = o;
  float4 dv;
  dv.x = rsqrtf((float)(v.x + 1));
  dv.y = rsqrtf((float)(v.y + 1));
  dv.z = rsqrtf((float)(v.z + 1));
  dv.w = rsqrtf((float)(v.w + 1));
  *(float4*)(dinv + base) = dv;
}

// ---------------- CSR scatter + per-edge (col, norm) packed int2 ----------------
__global__ __launch_bounds__(256) void k_scatter(const int* __restrict__ row,
                                                 const int* __restrict__ col,
                                                 const int* __restrict__ offs,
                                                 int* __restrict__ cursor,
                                                 const float* __restrict__ dinv,
                                                 int2* __restrict__ csr, int E) {
  int i = blockIdx.x * 256 + threadIdx.x;
  if (i >= E) return;
  int r = row[i];
  int c = col[i];
  int p = atomicAdd(&cursor[r], 1);
  int o = offs[r] + p;
  int2 cn;
  cn.x = c;
  cn.y = __float_as_int(dinv[r] * dinv[c]);
  csr[o] = cn;
}

// ---------------- cast+transpose weights, LDS-tiled (coalesced both sides) ----------------
__global__ __launch_bounds__(256) void k_cast_w(const float* __restrict__ W0,
                                                const float* __restrict__ W1,
                                                const float* __restrict__ W2,
                                                const float* __restrict__ P0,
                                                const float* __restrict__ P1,
                                                unsigned short* __restrict__ Wt) {
  __shared__ float tl[32][33];
  int b = blockIdx.x;
  int m = b >> 6;
  int t = b & 63;
  int tr = (t >> 3) * 32;  // k-tile
  int tc = (t & 7) * 32;   // n-tile
  const float* src = (m == 0) ? W0 : (m == 1) ? W1 : (m == 2) ? W2 : (m == 3) ? P0 : P1;
  int r = threadIdx.x >> 5, c = threadIdx.x & 31;
#pragma unroll
  for (int i = 0; i < 4; ++i)
    tl[r + i * 8][c] = src[(size_t)(tr + r + i * 8) * D + tc + c];
  __syncthreads();
#pragma unroll
  for (int i = 0; i < 4; ++i) {
    int n = tc + r + i * 8;
    int k = tr + c;
    Wt[(size_t)m * 65536 + (size_t)n * D + k] = f2bf(tl[c][r + i * 8]);
  }
}

// ---------------- emb fp32 -> bf16 (pad rows zeroed) ----------------
__global__ __launch_bounds__(256) void k_cast_emb(const float* __restrict__ emb,
                                                  unsigned short* __restrict__ XA, int N) {
  int idx = blockIdx.x * 256 + threadIdx.x;
  int i = idx >> 6;
  int c4 = (idx & 63) * 4;
  uint2 o;
  o.x = 0u;
  o.y = 0u;
  if (i < N) {
    float4 f = *(const float4*)(emb + (size_t)i * D + c4);
    o.x = (unsigned)f2bf(f.x) | ((unsigned)f2bf(f.y) << 16);
    o.y = (unsigned)f2bf(f.z) | ((unsigned)f2bf(f.w) << 16);
  }
  *(uint2*)(XA + (size_t)i * D + c4) = o;
}

// ---------------- GEMM: H8[Npad,256](fp8) = A[Npad,256](bf16) @ W ----------------
#define TLS 264
__global__ __launch_bounds__(256) void k_gemm(const unsigned short* __restrict__ A,
                                              const unsigned short* __restrict__ Bt,
                                              unsigned int* __restrict__ C8) {
  __shared__ unsigned short tile[64 * TLS];
  int tid = threadIdx.x;
  int lane = tid & 63;
  int w = tid >> 6;
  int quad = lane >> 4;
  int l15 = lane & 15;
  int m0 = blockIdx.x * 64;
  int arow = m0 + w * 16 + l15;
  f32x4 acc[16] = {};
#pragma unroll 2
  for (int k0 = 0; k0 < 256; k0 += 32) {
    short8 a = *(const short8*)(A + (size_t)arow * D + k0 + quad * 8);
#pragma unroll
    for (int t = 0; t < 16; ++t) {
      short8 b = *(const short8*)(Bt + (size_t)(t * 16 + l15) * D + k0 + quad * 8);
      acc[t] = __builtin_amdgcn_mfma_f32_16x16x32_bf16(a, b, acc[t], 0, 0, 0);
    }
  }
  int trow = w * 16 + quad * 4;
#pragma unroll
  for (int t = 0; t < 16; ++t)
#pragma unroll
    for (int r = 0; r < 4; ++r)
      tile[(trow + r) * TLS + t * 16 + l15] = f2bf(acc[t][r]);
  __syncthreads();
  int row = tid >> 2;
  int seg = tid & 3;
  const unsigned short* src = &tile[row * TLS + seg * 64];
  unsigned int* dst = C8 + (((size_t)(m0 + row) * D + seg * 64) >> 2);
#pragma unroll
  for (int k = 0; k < 4; ++k) {
    short8 x0 = *(const short8*)(src + k * 16);
    short8 x1 = *(const short8*)(src + k * 16 + 8);
    uint4 o;
    o.x = pk_fp8x4(bf2f((unsigned short)x0[0]), bf2f((unsigned short)x0[1]),
                   bf2f((unsigned short)x0[2]), bf2f((unsigned short)x0[3]));
    o.y = pk_fp8x4(bf2f((unsigned short)x0[4]), bf2f((unsigned short)x0[5]),
                   bf2f((unsigned short)x0[6]), bf2f((unsigned short)x0[7]));
    o.z = pk_fp8x4(bf2f((unsigned short)x1[0]), bf2f((unsigned short)x1[1]),
                   bf2f((unsigned short)x1[2]), bf2f((unsigned short)x1[3]));
    o.w = pk_fp8x4(bf2f((unsigned short)x1[4]), bf2f((unsigned short)x1[5]),
                   bf2f((unsigned short)x1[6]), bf2f((unsigned short)x1[7]));
    *(uint4*)(dst + k * 4) = o;
  }
}

// ---------------- CSR aggregation: 16 lanes per row, NT uint4 gathers, DEPTH-4 pipeline --
__global__ __launch_bounds__(256) void k_agg(const unsigned char* __restrict__ X8,
                                             const float* __restrict__ dinv,
                                             const int* __restrict__ offs,
                                             const int2* __restrict__ csr,
                                             const float* __restrict__ bias,
                                             unsigned short* __restrict__ xb,
                                             unsigned int* __restrict__ x8, int mode) {
  int tid = threadIdx.x;
  int w = tid >> 6;
  int lane = tid & 63;
  int s = lane >> 4;
  int l15 = lane & 15;
  int r = blockIdx.x * 16 + w * 4 + s;
  float dr = dinv[r];
  float wself = dr * dr;
  int es = offs[r], en = offs[r + 1];

  float acc[16];
  {
    u32x4 sv = ntload4(X8 + (size_t)r * 256 + l15 * 16);
    float f[16];
    up_fp8x4(sv.x, f[0], f[1], f[2], f[3]);
    up_fp8x4(sv.y, f[4], f[5], f[6], f[7]);
    up_fp8x4(sv.z, f[8], f[9], f[10], f[11]);
    up_fp8x4(sv.w, f[12], f[13], f[14], f[15]);
#pragma unroll
    for (int k = 0; k < 16; ++k) acc[k] = wself * f[k];
  }

  const int DEPTH = 4;
  float wns[DEPTH];
  u32x4 mm[DEPTH];
#pragma unroll
  for (int j = 0; j < DEPTH; ++j) {
    bool v = (es + j) < en;
    int idx = v ? (es + j) : 0;
    int col;
    float wn;
    ntload_cn(csr + idx, col, wn);
    col = v ? col : 0;
    wns[j] = v ? wn : 0.f;
    mm[j] = ntload4(X8 + (size_t)col * 256 + l15 * 16);
  }

  for (int e = es; e < en; e += DEPTH) {
    float nwns[DEPTH];
    u32x4 nmm[DEPTH];
#pragma unroll
    for (int j = 0; j < DEPTH; ++j) {
      bool v = (e + DEPTH + j) < en;
      int idx = v ? (e + DEPTH + j) : 0;
      int col;
      float wn;
      ntload_cn(csr + idx, col, wn);
      col = v ? col : 0;
      nwns[j] = v ? wn : 0.f;
      nmm[j] = ntload4(X8 + (size_t)col * 256 + l15 * 16);
    }
#pragma unroll
    for (int j = 0; j < DEPTH; ++j) {
      float f[16];
      up_fp8x4(mm[j].x, f[0], f[1], f[2], f[3]);
      up_fp8x4(mm[j].y, f[4], f[5], f[6], f[7]);
      up_fp8x4(mm[j].z, f[8], f[9], f[10], f[11]);
      up_fp8x4(mm[j].w, f[12], f[13], f[14], f[15]);
#pragma unroll
      for (int k = 0; k < 16; ++k) acc[k] += wns[j] * f[k];
    }
#pragma unroll
    for (int j = 0; j < DEPTH; ++j) {
      mm[j] = nmm[j];
      wns[j] = nwns[j];
    }
  }

#pragma unroll
  for (int k = 0; k < 4; ++k) {
    float4 bb = *(const float4*)(bias + l15 * 16 + k * 4);
    acc[k * 4 + 0] += bb.x;
    acc[k * 4 + 1] += bb.y;
    acc[k * 4 + 2] += bb.z;
    acc[k * 4 + 3] += bb.w;
  }
  if (mode == 0) {
#pragma unroll
    for (int k = 0; k < 16; ++k) acc[k] = fmaxf(acc[k], 0.f);
    uint4 o0, o1;
    o0.x = (unsigned)f2bf(acc[0]) | ((unsigned)f2bf(acc[1]) << 16);
    o0.y = (unsigned)f2bf(acc[2]) | ((unsigned)f2bf(acc[3]) << 16);
    o0.z = (unsigned)f2bf(acc[4]) | ((unsigned)f2bf(acc[5]) << 16);
    o0.w = (unsigned)f2bf(acc[6]) | ((unsigned)f2bf(acc[7]) << 16);
    o1.x = (unsigned)f2bf(acc[8]) | ((unsigned)f2bf(acc[9]) << 16);
    o1.y = (unsigned)f2bf(acc[10]) | ((unsigned)f2bf(acc[11]) << 16);
    o1.z = (unsigned)f2bf(acc[12]) | ((unsigned)f2bf(acc[13]) << 16);
    o1.w = (unsigned)f2bf(acc[14]) | ((unsigned)f2bf(acc[15]) << 16);
    unsigned short* dst = xb + (size_t)r * D + l15 * 16;
    *(uint4*)dst = o0;
    *(uint4*)(dst + 8) = o1;
  } else {
    uint4 o;
    o.x = pk_fp8x4(acc[0], acc[1], acc[2], acc[3]);
    o.y = pk_fp8x4(acc[4], acc[5], acc[6], acc[7]);
    o.z = pk_fp8x4(acc[8], acc[9], acc[10], acc[11]);
    o.w = pk_fp8x4(acc[12], acc[13], acc[14], acc[15]);
    *(uint4*)(x8 + (size_t)r * 64 + l15 * 4) = o;
  }
}

// ---------------- fused link predictor (fp8 NT gather) ----------------
#define LPS 264
__global__ __launch_bounds__(256, 4) void k_lp(const unsigned char* __restrict__ X8,
                                               const int* __restrict__ eu,
                                               const int* __restrict__ ev,
                                               const unsigned short* __restrict__ P0t,
                                               const float* __restrict__ pb0,
                                               const unsigned short* __restrict__ P1t,
                                               const float* __restrict__ pb1,
                                               const float* __restrict__ P2,
                                               const float* __restrict__ pb2,
                                               float* __restrict__ out, int Q) {
  __shared__ unsigned short hA[64 * LPS];
  __shared__ float sred[4][64];
  int tid = threadIdx.x;
  int lane = tid & 63;
  int w = tid >> 6;
  int quad = lane >> 4;
  int l15 = lane & 15;
  int q0 = blockIdx.x * 64;

  // ---- gather: 4 threads per query; fp8 rows (256 B); 8 x 16B NT loads in flight
  {
    int qi = tid >> 2;
    int seg = tid & 3;
    int q = q0 + qi;
    int u = 0, v = 0;
    if (q < Q) { u = eu[q]; v = ev[q]; }
    const unsigned char* pu = X8 + (size_t)u * 256 + seg * 64;
    const unsigned char* pv = X8 + (size_t)v * 256 + seg * 64;
    u32x4 ru[4], rv[4];
#pragma unroll
    for (int c = 0; c < 4; ++c) {
      ru[c] = ntload4(pu + c * 16);
      rv[c] = ntload4(pv + c * 16);
    }
#pragma unroll
    for (int c = 0; c < 4; ++c) {
      float uf[16], vf[16];
      up_fp8x4(ru[c].x, uf[0], uf[1], uf[2], uf[3]);
      up_fp8x4(ru[c].y, uf[4], uf[5], uf[6], uf[7]);
      up_fp8x4(ru[c].z, uf[8], uf[9], uf[10], uf[11]);
      up_fp8x4(ru[c].w, uf[12], uf[13], uf[14], uf[15]);
      up_fp8x4(rv[c].x, vf[0], vf[1], vf[2], vf[3]);
      up_fp8x4(rv[c].y, vf[4], vf[5], vf[6], vf[7]);
      up_fp8x4(rv[c].z, vf[8], vf[9], vf[10], vf[11]);
      up_fp8x4(rv[c].w, vf[12], vf[13], vf[14], vf[15]);
      uint4 o0, o1;
      if (q < Q) {
        o0.x = packtrunc(uf[0] * vf[0], uf[1] * vf[1]);
        o0.y = packtrunc(uf[2] * vf[2], uf[3] * vf[3]);
        o0.z = packtrunc(uf[4] * vf[4], uf[5] * vf[5]);
        o0.w = packtrunc(uf[6] * vf[6], uf[7] * vf[7]);
        o1.x = packtrunc(uf[8] * vf[8], uf[9] * vf[9]);
        o1.y = packtrunc(uf[10] * vf[10], uf[11] * vf[11]);
        o1.z = packtrunc(uf[12] * vf[12], uf[13] * vf[13]);
        o1.w = packtrunc(uf[14] * vf[14], uf[15] * vf[15]);
      } else {
        o0.x = o0.y = o0.z = o0.w = 0u;
        o1.x = o1.y = o1.z = o1.w = 0u;
      }
      int off = seg * 64 + c * 16;
      *(uint4*)&hA[qi * LPS + off] = o0;
      *(uint4*)&hA[qi * LPS + off + 8] = o1;
    }
  }
  __syncthreads();

  // ---- layer 0: hA <- relu(hA @ P0t + pb0)
  {
    f32x4 acc[4][4] = {};
#pragma unroll
    for (int k0 = 0; k0 < 256; k0 += 32) {
      short8 a[4];
#pragma unroll
      for (int ms = 0; ms < 4; ++ms)
        a[ms] = *(const short8*)&hA[(ms * 16 + l15) * LPS + k0 + quad * 8];
#pragma unroll
      for (int ns = 0; ns < 4; ++ns) {
        short8 b = *(const short8*)(P0t + (size_t)(w * 64 + ns * 16 + l15) * D + k0 + quad * 8);
#pragma unroll
        for (int ms = 0; ms < 4; ++ms)
          acc[ms][ns] = __builtin_amdgcn_mfma_f32_16x16x32_bf16(a[ms], b, acc[ms][ns], 0, 0, 0);
      }
    }
    __syncthreads();
#pragma unroll
    for (int ns = 0; ns < 4; ++ns) {
      int col = w * 64 + ns * 16 + l15;
      float bv = pb0[col];
#pragma unroll
      for (int ms = 0; ms < 4; ++ms) {
        int rbase = ms * 16 + quad * 4;
#pragma unroll
        for (int r = 0; r < 4; ++r) {
          float vv = fmaxf(acc[ms][ns][r] + bv, 0.f);
          hA[(rbase + r) * LPS + col] = f2bf(vv);
        }
      }
    }
    __syncthreads();
  }

  // ---- layer 1 + fused P2 dot + sigmoid
  {
    f32x4 acc[4][4] = {};
#pragma unroll
    for (int k0 = 0; k0 < 256; k0 += 32) {
      short8 a[4];
#pragma unroll
      for (int ms = 0; ms < 4; ++ms)
        a[ms] = *(const short8*)&hA[(ms * 16 + l15) * LPS + k0 + quad * 8];
#pragma unroll
      for (int ns = 0; ns < 4; ++ns) {
        short8 b = *(const short8*)(P1t + (size_t)(w * 64 + ns * 16 + l15) * D + k0 + quad * 8);
#pragma unroll
        for (int ms = 0; ms < 4; ++ms)
          acc[ms][ns] = __builtin_amdgcn_mfma_f32_16x16x32_bf16(a[ms], b, acc[ms][ns], 0, 0, 0);
      }
    }
    float p2v[4], pbv[4];
#pragma unroll
    for (int ns = 0; ns < 4; ++ns) {
      int col = w * 64 + ns * 16 + l15;
      p2v[ns] = P2[col];
      pbv[ns] = pb1[col];
    }
    float part[16];
#pragma unroll
    for (int ms = 0; ms < 4; ++ms)
#pragma unroll
      for (int r = 0; r < 4; ++r) {
        float s = 0.f;
#pragma unroll
        for (int ns = 0; ns < 4; ++ns)
          s += fmaxf(acc[ms][ns][r] + pbv[ns], 0.f) * p2v[ns];
        part[ms * 4 + r] = s;
      }
#pragma unroll
    for (int d = 1; d < 16; d <<= 1)
#pragma unroll
      for (int i = 0; i < 16; ++i) part[i] += __shfl_xor(part[i], d, 64);
    if (l15 == 0) {
#pragma unroll
      for (int i = 0; i < 16; ++i) {
        int ms = i >> 2, r = i & 3;
        sred[w][ms * 16 + quad * 4 + r] = part[i];
      }
    }
    __syncthreads();
    if (tid < 64) {
      float s = sred[0][tid] + sred[1][tid] + sred[2][tid] + sred[3][tid] + pb2[0];
      int qq = q0 + tid;
      if (qq < Q) out[qq] = 1.f / (1.f + expf(-s));
    }
  }
}

extern "C" void kernel_launch(void* const* d_in, const int* in_sizes, int n_in,
                              void* d_out, int out_size, void* d_ws, size_t ws_size,
                              hipStream_t stream) {
  const int* adj_row = (const int*)d_in[0];
  const int* adj_col = (const int*)d_in[1];
  const int* edges = (const int*)d_in[2];
  const float* emb = (const float*)d_in[3];
  const float* W0 = (const float*)d_in[4];
  const float* b0 = (const float*)d_in[5];
  const float* W1 = (const float*)d_in[6];
  const float* b1 = (const float*)d_in[7];
  const float* W2 = (const float*)d_in[8];
  const float* b2 = (const float*)d_in[9];
  const float* P0 = (const float*)d_in[10];
  const float* pb0 = (const float*)d_in[11];
  const float* P1 = (const float*)d_in[12];
  const float* pb1 = (const float*)d_in[13];
  const float* P2 = (const float*)d_in[14];
  const float* pb2 = (const float*)d_in[15];
  float* out = (float*)d_out;

  int E = in_sizes[0];
  int Q = in_sizes[2] / 2;
  int N = in_sizes[3] / D;
  int Npad = ((N + 63) / 64) * 64;
  int Npad2 = ((N + 1023) / 1024) * 1024;
  int nb = Npad2 / 1024;

  char* p = (char*)d_ws;
  auto alloc = [&](size_t bytes) {
    char* r = p;
    p += (bytes + 255) & ~(size_t)255;
    return r;
  };
  int* cnt = (int*)alloc((size_t)Npad2 * 4);
  int* cursor = (int*)alloc((size_t)Npad2 * 4);
  int* offs = (int*)alloc((size_t)(Npad2 + 1) * 4);
  float* dinv = (float*)alloc((size_t)Npad2 * 4);
  int* bsum = (int*)alloc((size_t)nb * 4);
  int2* csr = (int2*)alloc((size_t)E * 8);
  unsigned short* Wt = (unsigned short*)alloc((size_t)5 * 65536 * 2);
  unsigned short* XA = (unsigned short*)alloc((size_t)Npad * D * 2);
  unsigned int* XC8 = (unsigned int*)alloc((size_t)Npad * D);
  unsigned int* XA8 = (unsigned int*)XA;  // alias: XA(bf16) dead when layer-2 agg writes fp8

  hipMemsetAsync(cnt, 0, (size_t)Npad2 * 4, stream);
  hipMemsetAsync(cursor, 0, (size_t)Npad2 * 4, stream);

  int eb = (E + 255) / 256;
  k_count<<<eb, 256, 0, stream>>>(adj_row, cnt, E);
  k_scan1<<<nb, 256, 0, stream>>>(cnt, bsum);
  k_scan2<<<1, 256, 0, stream>>>(bsum, nb, offs + Npad2);
  k_scan3<<<nb, 256, 0, stream>>>(cnt, bsum, offs, dinv);
  k_scatter<<<eb, 256, 0, stream>>>(adj_row, adj_col, offs, cursor, dinv, csr, E);
  k_cast_w<<<5 * 64, 256, 0, stream>>>(W0, W1, W2, P0, P1, Wt);
  k_cast_emb<<<Npad / 4, 256, 0, stream>>>(emb, XA, N);

  const float* biases[3] = {b0, b1, b2};
  for (int l = 0; l < 3; ++l) {
    k_gemm<<<Npad / 64, 256, 0, stream>>>(XA, Wt + (size_t)l * 65536, XC8);
    k_agg<<<Npad / 16, 256, 0, stream>>>((const unsigned char*)XC8, dinv, offs, csr,
                                         biases[l], XA, XA8, (l < 2) ? 0 : 1);
  }
  k_lp<<<(Q + 63) / 64, 256, 0, stream>>>((const unsigned char*)XA8, edges, edges + Q,
                                          Wt + (size_t)3 * 65536, pb0,
                                          Wt + (size_t)4 * 65536, pb1, P2, pb2, out, Q);
}

// Round 8
// 1080.971 us; speedup vs baseline: 1.2342x; 1.2342x over previous
//
#include <hip/hip_runtime.h>
#include <math.h>

#define D 256

typedef short short8 __attribute__((ext_vector_type(8)));
typedef float f32x4 __attribute__((ext_vector_type(4)));
typedef float f32x2 __attribute__((ext_vector_type(2)));

__device__ __forceinline__ float bf2f(unsigned int h) {
  return __uint_as_float(h << 16);
}
__device__ __forceinline__ unsigned short f2bf(float f) {
  unsigned int u = __float_as_uint(f);
  u += 0x7fffu + ((u >> 16) & 1u);
  return (unsigned short)(u >> 16);
}
__device__ __forceinline__ unsigned int packtrunc(float a, float b) {
  return (__float_as_uint(a) >> 16) | (__float_as_uint(b) & 0xffff0000u);
}
__device__ __forceinline__ unsigned int pk_fp8x4(float a, float b, float c, float d) {
  unsigned int r = 0;
  r = __builtin_amdgcn_cvt_pk_fp8_f32(a, b, r, false);
  r = __builtin_amdgcn_cvt_pk_fp8_f32(c, d, r, true);
  return r;
}
__device__ __forceinline__ void up_fp8x4(unsigned int x, float& a, float& b, float& c,
                                         float& d) {
  f32x2 lo = __builtin_amdgcn_cvt_pk_f32_fp8(x, false);
  f32x2 hi = __builtin_amdgcn_cvt_pk_f32_fp8(x, true);
  a = lo.x; b = lo.y; c = hi.x; d = hi.y;
}

// ---------------- degree count ----------------
__global__ __launch_bounds__(256) void k_count(const int* __restrict__ row,
                                               int* __restrict__ cnt, int E) {
  int i = blockIdx.x * 256 + threadIdx.x;
  if (i < E) atomicAdd(&cnt[row[i]], 1);
}

// ---------------- 3-phase exclusive scan over Npad2 (multiple of 1024) ----------------
__global__ __launch_bounds__(256) void k_scan1(const int* __restrict__ cnt,
                                               int* __restrict__ bsum) {
  __shared__ int sw[4];
  int b = blockIdx.x, tid = threadIdx.x, lane = tid & 63, w = tid >> 6;
  int4 v = *(const int4*)(cnt + (size_t)b * 1024 + tid * 4);
  int s = v.x + v.y + v.z + v.w;
#pragma unroll
  for (int d = 32; d; d >>= 1) s += __shfl_xor(s, d, 64);
  if (lane == 0) sw[w] = s;
  __syncthreads();
  if (tid == 0) bsum[b] = sw[0] + sw[1] + sw[2] + sw[3];
}

__global__ __launch_bounds__(256) void k_scan2(int* __restrict__ bsum, int nb,
                                               int* __restrict__ offs_end) {
  __shared__ int sw[4];
  int tid = threadIdx.x, lane = tid & 63, w = tid >> 6;
  int v = (tid < nb) ? bsum[tid] : 0;
  int x = v;
#pragma unroll
  for (int d = 1; d < 64; d <<= 1) {
    int y = __shfl_up(x, d, 64);
    if (lane >= d) x += y;
  }
  if (lane == 63) sw[w] = x;
  __syncthreads();
  int woff = 0;
  for (int i = 0; i < w; ++i) woff += sw[i];
  int incl = woff + x;
  if (tid < nb) bsum[tid] = incl - v;
  if (tid == 0) *offs_end = sw[0] + sw[1] + sw[2] + sw[3];
}

__global__ __launch_bounds__(256) void k_scan3(const int* __restrict__ cnt,
                                               const int* __restrict__ bbase,
                                               int* __restrict__ offs,
                                               float* __restrict__ dinv) {
  __shared__ int sw[4];
  int b = blockIdx.x, tid = threadIdx.x, lane = tid & 63, w = tid >> 6;
  size_t base = (size_t)b * 1024 + tid * 4;
  int4 v = *(const int4*)(cnt + base);
  int s = v.x + v.y + v.z + v.w;
  int x = s;
#pragma unroll
  for (int d = 1; d < 64; d <<= 1) {
    int y = __shfl_up(x, d, 64);
    if (lane >= d) x += y;
  }
  if (lane == 63) sw[w] = x;
  __syncthreads();
  int woff = bbase[b];
  for (int i = 0; i < w; ++i) woff += sw[i];
  int excl = woff + x - s;
  int4 o;
  o.x = excl;
  o.y = excl + v.x;
  o.z = o.y + v.y;
  o.w = o.z + v.z;
  *(int4*)(offs + base) = o;
  float4 dv;
  dv.x = rsqrtf((float)(v.x + 1));
  dv.y = rsqrtf((float)(v.y + 1));
  dv.z = rsqrtf((float)(v.z + 1));
  dv.w = rsqrtf((float)(v.w + 1));
  *(float4*)(dinv + base) = dv;
}

// ---------------- CSR scatter + per-edge (col, norm) packed int2 ----------------
__global__ __launch_bounds__(256) void k_scatter(const int* __restrict__ row,
                                                 const int* __restrict__ col,
                                                 const int* __restrict__ offs,
                                                 int* __restrict__ cursor,
                                                 const float* __restrict__ dinv,
                                                 int2* __restrict__ csr, int E) {
  int i = blockIdx.x * 256 + threadIdx.x;
  if (i >= E) return;
  int r = row[i];
  int c = col[i];
  int p = atomicAdd(&cursor[r], 1);
  int o = offs[r] + p;
  int2 cn;
  cn.x = c;
  cn.y = __float_as_int(dinv[r] * dinv[c]);
  csr[o] = cn;
}

// ---------------- cast+transpose weights, LDS-tiled (coalesced both sides) ----------------
__global__ __launch_bounds__(256) void k_cast_w(const float* __restrict__ W0,
                                                const float* __restrict__ W1,
                                                const float* __restrict__ W2,
                                                const float* __restrict__ P0,
                                                const float* __restrict__ P1,
                                                unsigned short* __restrict__ Wt) {
  __shared__ float tl[32][33];
  int b = blockIdx.x;
  int m = b >> 6;
  int t = b & 63;
  int tr = (t >> 3) * 32;  // k-tile
  int tc = (t & 7) * 32;   // n-tile
  const float* src = (m == 0) ? W0 : (m == 1) ? W1 : (m == 2) ? W2 : (m == 3) ? P0 : P1;
  int r = threadIdx.x >> 5, c = threadIdx.x & 31;
#pragma unroll
  for (int i = 0; i < 4; ++i)
    tl[r + i * 8][c] = src[(size_t)(tr + r + i * 8) * D + tc + c];
  __syncthreads();
#pragma unroll
  for (int i = 0; i < 4; ++i) {
    int n = tc + r + i * 8;
    int k = tr + c;
    Wt[(size_t)m * 65536 + (size_t)n * D + k] = f2bf(tl[c][r + i * 8]);
  }
}

// ---------------- emb fp32 -> bf16 (pad rows zeroed) ----------------
__global__ __launch_bounds__(256) void k_cast_emb(const float* __restrict__ emb,
                                                  unsigned short* __restrict__ XA, int N) {
  int idx = blockIdx.x * 256 + threadIdx.x;
  int i = idx >> 6;
  int c4 = (idx & 63) * 4;
  uint2 o;
  o.x = 0u;
  o.y = 0u;
  if (i < N) {
    float4 f = *(const float4*)(emb + (size_t)i * D + c4);
    o.x = (unsigned)f2bf(f.x) | ((unsigned)f2bf(f.y) << 16);
    o.y = (unsigned)f2bf(f.z) | ((unsigned)f2bf(f.w) << 16);
  }
  *(uint2*)(XA + (size_t)i * D + c4) = o;
}

// ---------------- GEMM: H8[Npad,256](fp8) = A[Npad,256](bf16) @ W ----------------
// B K-slice staged in LDS once per block (was: every wave re-reads B from global).
#define TLS 264
__global__ __launch_bounds__(256) void k_gemm(const unsigned short* __restrict__ A,
                                              const unsigned short* __restrict__ Bt,
                                              unsigned int* __restrict__ C8) {
  __shared__ unsigned short smem[64 * TLS];  // 33 KB: B-stage (20 KB) then C tile
  int tid = threadIdx.x;
  int lane = tid & 63;
  int w = tid >> 6;
  int quad = lane >> 4;
  int l15 = lane & 15;
  int m0 = blockIdx.x * 64;
  int arow = m0 + w * 16 + l15;
  f32x4 acc[16] = {};
  const uint4* gb = (const uint4*)(Bt + (size_t)tid * D);  // thread tid owns B-row tid
#pragma unroll 1
  for (int k0 = 0; k0 < 256; k0 += 32) {
    int gi = k0 >> 3;
    uint4 b0 = gb[gi + 0];
    uint4 b1 = gb[gi + 1];
    uint4 b2 = gb[gi + 2];
    uint4 b3 = gb[gi + 3];
    short8 a = *(const short8*)(A + (size_t)arow * D + k0 + quad * 8);
    __syncthreads();  // previous iteration's LDS reads complete
    *(uint4*)&smem[tid * 40 + 0] = b0;
    *(uint4*)&smem[tid * 40 + 8] = b1;
    *(uint4*)&smem[tid * 40 + 16] = b2;
    *(uint4*)&smem[tid * 40 + 24] = b3;
    __syncthreads();
#pragma unroll
    for (int t = 0; t < 16; ++t) {
      short8 b = *(const short8*)&smem[(t * 16 + l15) * 40 + quad * 8];
      acc[t] = __builtin_amdgcn_mfma_f32_16x16x32_bf16(a, b, acc[t], 0, 0, 0);
    }
  }
  __syncthreads();  // before reusing smem as output tile
  int trow = w * 16 + quad * 4;
#pragma unroll
  for (int t = 0; t < 16; ++t)
#pragma unroll
    for (int r = 0; r < 4; ++r)
      smem[(trow + r) * TLS + t * 16 + l15] = f2bf(acc[t][r]);
  __syncthreads();
  int row = tid >> 2;
  int seg = tid & 3;
  const unsigned short* src = &smem[row * TLS + seg * 64];
  unsigned int* dst = C8 + (((size_t)(m0 + row) * D + seg * 64) >> 2);
#pragma unroll
  for (int k = 0; k < 4; ++k) {
    short8 x0 = *(const short8*)(src + k * 16);
    short8 x1 = *(const short8*)(src + k * 16 + 8);
    uint4 o;
    o.x = pk_fp8x4(bf2f((unsigned short)x0[0]), bf2f((unsigned short)x0[1]),
                   bf2f((unsigned short)x0[2]), bf2f((unsigned short)x0[3]));
    o.y = pk_fp8x4(bf2f((unsigned short)x0[4]), bf2f((unsigned short)x0[5]),
                   bf2f((unsigned short)x0[6]), bf2f((unsigned short)x0[7]));
    o.z = pk_fp8x4(bf2f((unsigned short)x1[0]), bf2f((unsigned short)x1[1]),
                   bf2f((unsigned short)x1[2]), bf2f((unsigned short)x1[3]));
    o.w = pk_fp8x4(bf2f((unsigned short)x1[4]), bf2f((unsigned short)x1[5]),
                   bf2f((unsigned short)x1[6]), bf2f((unsigned short)x1[7]));
    *(uint4*)(dst + k * 4) = o;
  }
}

// ---------------- CSR aggregation: 16 lanes per row, uint4 gathers, DEPTH-6 pipeline ----
__global__ __launch_bounds__(256) void k_agg(const unsigned char* __restrict__ X8,
                                             const float* __restrict__ dinv,
                                             const int* __restrict__ offs,
                                             const int2* __restrict__ csr,
                                             const float* __restrict__ bias,
                                             unsigned short* __restrict__ xb,
                                             unsigned int* __restrict__ x8, int mode) {
  int tid = threadIdx.x;
  int w = tid >> 6;
  int lane = tid & 63;
  int s = lane >> 4;
  int l15 = lane & 15;
  int r = blockIdx.x * 16 + w * 4 + s;
  float dr = dinv[r];
  float wself = dr * dr;
  int es = offs[r], en = offs[r + 1];

  float acc[16];
  {
    uint4 sv = *(const uint4*)(X8 + (size_t)r * 256 + l15 * 16);
    float f[16];
    up_fp8x4(sv.x, f[0], f[1], f[2], f[3]);
    up_fp8x4(sv.y, f[4], f[5], f[6], f[7]);
    up_fp8x4(sv.z, f[8], f[9], f[10], f[11]);
    up_fp8x4(sv.w, f[12], f[13], f[14], f[15]);
#pragma unroll
    for (int k = 0; k < 16; ++k) acc[k] = wself * f[k];
  }

  const int DEPTH = 6;
  float wns[DEPTH];
  uint4 mm[DEPTH];
#pragma unroll
  for (int j = 0; j < DEPTH; ++j) {
    bool v = (es + j) < en;
    int idx = v ? (es + j) : 0;
    int2 cn = csr[idx];
    int col = v ? cn.x : 0;
    wns[j] = v ? __int_as_float(cn.y) : 0.f;
    mm[j] = *(const uint4*)(X8 + (size_t)col * 256 + l15 * 16);
  }

  for (int e = es; e < en; e += DEPTH) {
    float nwns[DEPTH];
    uint4 nmm[DEPTH];
#pragma unroll
    for (int j = 0; j < DEPTH; ++j) {
      bool v = (e + DEPTH + j) < en;
      int idx = v ? (e + DEPTH + j) : 0;
      int2 cn = csr[idx];
      int col = v ? cn.x : 0;
      nwns[j] = v ? __int_as_float(cn.y) : 0.f;
      nmm[j] = *(const uint4*)(X8 + (size_t)col * 256 + l15 * 16);
    }
#pragma unroll
    for (int j = 0; j < DEPTH; ++j) {
      float f[16];
      up_fp8x4(mm[j].x, f[0], f[1], f[2], f[3]);
      up_fp8x4(mm[j].y, f[4], f[5], f[6], f[7]);
      up_fp8x4(mm[j].z, f[8], f[9], f[10], f[11]);
      up_fp8x4(mm[j].w, f[12], f[13], f[14], f[15]);
#pragma unroll
      for (int k = 0; k < 16; ++k) acc[k] += wns[j] * f[k];
    }
#pragma unroll
    for (int j = 0; j < DEPTH; ++j) {
      mm[j] = nmm[j];
      wns[j] = nwns[j];
    }
  }

#pragma unroll
  for (int k = 0; k < 4; ++k) {
    float4 bb = *(const float4*)(bias + l15 * 16 + k * 4);
    acc[k * 4 + 0] += bb.x;
    acc[k * 4 + 1] += bb.y;
    acc[k * 4 + 2] += bb.z;
    acc[k * 4 + 3] += bb.w;
  }
  if (mode == 0) {
#pragma unroll
    for (int k = 0; k < 16; ++k) acc[k] = fmaxf(acc[k], 0.f);
    uint4 o0, o1;
    o0.x = (unsigned)f2bf(acc[0]) | ((unsigned)f2bf(acc[1]) << 16);
    o0.y = (unsigned)f2bf(acc[2]) | ((unsigned)f2bf(acc[3]) << 16);
    o0.z = (unsigned)f2bf(acc[4]) | ((unsigned)f2bf(acc[5]) << 16);
    o0.w = (unsigned)f2bf(acc[6]) | ((unsigned)f2bf(acc[7]) << 16);
    o1.x = (unsigned)f2bf(acc[8]) | ((unsigned)f2bf(acc[9]) << 16);
    o1.y = (unsigned)f2bf(acc[10]) | ((unsigned)f2bf(acc[11]) << 16);
    o1.z = (unsigned)f2bf(acc[12]) | ((unsigned)f2bf(acc[13]) << 16);
    o1.w = (unsigned)f2bf(acc[14]) | ((unsigned)f2bf(acc[15]) << 16);
    unsigned short* dst = xb + (size_t)r * D + l15 * 16;
    *(uint4*)dst = o0;
    *(uint4*)(dst + 8) = o1;
  } else {
    uint4 o;
    o.x = pk_fp8x4(acc[0], acc[1], acc[2], acc[3]);
    o.y = pk_fp8x4(acc[4], acc[5], acc[6], acc[7]);
    o.z = pk_fp8x4(acc[8], acc[9], acc[10], acc[11]);
    o.w = pk_fp8x4(acc[12], acc[13], acc[14], acc[15]);
    *(uint4*)(x8 + (size_t)r * 64 + l15 * 4) = o;
  }
}

// ---------------- fused link predictor (fp8 gather, plain loads) ----------------
#define LPS 264
__global__ __launch_bounds__(256, 4) void k_lp(const unsigned char* __restrict__ X8,
                                               const int* __restrict__ eu,
                                               const int* __restrict__ ev,
                                               const unsigned short* __restrict__ P0t,
                                               const float* __restrict__ pb0,
                                               const unsigned short* __restrict__ P1t,
                                               const float* __restrict__ pb1,
                                               const float* __restrict__ P2,
                                               const float* __restrict__ pb2,
                                               float* __restrict__ out, int Q) {
  __shared__ unsigned short hA[64 * LPS];
  __shared__ float sred[4][64];
  int tid = threadIdx.x;
  int lane = tid & 63;
  int w = tid >> 6;
  int quad = lane >> 4;
  int l15 = lane & 15;
  int q0 = blockIdx.x * 64;

  // ---- gather: 4 threads per query; fp8 rows (256 B); 8 x 16B loads in flight
  {
    int qi = tid >> 2;
    int seg = tid & 3;
    int q = q0 + qi;
    int u = 0, v = 0;
    if (q < Q) { u = eu[q]; v = ev[q]; }
    const uint4* pu = (const uint4*)(X8 + (size_t)u * 256 + seg * 64);
    const uint4* pv = (const uint4*)(X8 + (size_t)v * 256 + seg * 64);
    uint4 ru[4], rv[4];
#pragma unroll
    for (int c = 0; c < 4; ++c) { ru[c] = pu[c]; rv[c] = pv[c]; }
#pragma unroll
    for (int c = 0; c < 4; ++c) {
      float uf[16], vf[16];
      up_fp8x4(ru[c].x, uf[0], uf[1], uf[2], uf[3]);
      up_fp8x4(ru[c].y, uf[4], uf[5], uf[6], uf[7]);
      up_fp8x4(ru[c].z, uf[8], uf[9], uf[10], uf[11]);
      up_fp8x4(ru[c].w, uf[12], uf[13], uf[14], uf[15]);
      up_fp8x4(rv[c].x, vf[0], vf[1], vf[2], vf[3]);
      up_fp8x4(rv[c].y, vf[4], vf[5], vf[6], vf[7]);
      up_fp8x4(rv[c].z, vf[8], vf[9], vf[10], vf[11]);
      up_fp8x4(rv[c].w, vf[12], vf[13], vf[14], vf[15]);
      uint4 o0, o1;
      if (q < Q) {
        o0.x = packtrunc(uf[0] * vf[0], uf[1] * vf[1]);
        o0.y = packtrunc(uf[2] * vf[2], uf[3] * vf[3]);
        o0.z = packtrunc(uf[4] * vf[4], uf[5] * vf[5]);
        o0.w = packtrunc(uf[6] * vf[6], uf[7] * vf[7]);
        o1.x = packtrunc(uf[8] * vf[8], uf[9] * vf[9]);
        o1.y = packtrunc(uf[10] * vf[10], uf[11] * vf[11]);
        o1.z = packtrunc(uf[12] * vf[12], uf[13] * vf[13]);
        o1.w = packtrunc(uf[14] * vf[14], uf[15] * vf[15]);
      } else {
        o0.x = o0.y = o0.z = o0.w = 0u;
        o1.x = o1.y = o1.z = o1.w = 0u;
      }
      int off = seg * 64 + c * 16;
      *(uint4*)&hA[qi * LPS + off] = o0;
      *(uint4*)&hA[qi * LPS + off + 8] = o1;
    }
  }
  __syncthreads();

  // ---- layer 0: hA <- relu(hA @ P0t + pb0)
  {
    f32x4 acc[4][4] = {};
#pragma unroll
    for (int k0 = 0; k0 < 256; k0 += 32) {
      short8 a[4];
#pragma unroll
      for (int ms = 0; ms < 4; ++ms)
        a[ms] = *(const short8*)&hA[(ms * 16 + l15) * LPS + k0 + quad * 8];
#pragma unroll
      for (int ns = 0; ns < 4; ++ns) {
        short8 b = *(const short8*)(P0t + (size_t)(w * 64 + ns * 16 + l15) * D + k0 + quad * 8);
#pragma unroll
        for (int ms = 0; ms < 4; ++ms)
          acc[ms][ns] = __builtin_amdgcn_mfma_f32_16x16x32_bf16(a[ms], b, acc[ms][ns], 0, 0, 0);
      }
    }
    __syncthreads();
#pragma unroll
    for (int ns = 0; ns < 4; ++ns) {
      int col = w * 64 + ns * 16 + l15;
      float bv = pb0[col];
#pragma unroll
      for (int ms = 0; ms < 4; ++ms) {
        int rbase = ms * 16 + quad * 4;
#pragma unroll
        for (int r = 0; r < 4; ++r) {
          float vv = fmaxf(acc[ms][ns][r] + bv, 0.f);
          hA[(rbase + r) * LPS + col] = f2bf(vv);
        }
      }
    }
    __syncthreads();
  }

  // ---- layer 1 + fused P2 dot + sigmoid
  {
    f32x4 acc[4][4] = {};
#pragma unroll
    for (int k0 = 0; k0 < 256; k0 += 32) {
      short8 a[4];
#pragma unroll
      for (int ms = 0; ms < 4; ++ms)
        a[ms] = *(const short8*)&hA[(ms * 16 + l15) * LPS + k0 + quad * 8];
#pragma unroll
      for (int ns = 0; ns < 4; ++ns) {
        short8 b = *(const short8*)(P1t + (size_t)(w * 64 + ns * 16 + l15) * D + k0 + quad * 8);
#pragma unroll
        for (int ms = 0; ms < 4; ++ms)
          acc[ms][ns] = __builtin_amdgcn_mfma_f32_16x16x32_bf16(a[ms], b, acc[ms][ns], 0, 0, 0);
      }
    }
    float p2v[4], pbv[4];
#pragma unroll
    for (int ns = 0; ns < 4; ++ns) {
      int col = w * 64 + ns * 16 + l15;
      p2v[ns] = P2[col];
      pbv[ns] = pb1[col];
    }
    float part[16];
#pragma unroll
    for (int ms = 0; ms < 4; ++ms)
#pragma unroll
      for (int r = 0; r < 4; ++r) {
        float s = 0.f;
#pragma unroll
        for (int ns = 0; ns < 4; ++ns)
          s += fmaxf(acc[ms][ns][r] + pbv[ns], 0.f) * p2v[ns];
        part[ms * 4 + r] = s;
      }
#pragma unroll
    for (int d = 1; d < 16; d <<= 1)
#pragma unroll
      for (int i = 0; i < 16; ++i) part[i] += __shfl_xor(part[i], d, 64);
    if (l15 == 0) {
#pragma unroll
      for (int i = 0; i < 16; ++i) {
        int ms = i >> 2, r = i & 3;
        sred[w][ms * 16 + quad * 4 + r] = part[i];
      }
    }
    __syncthreads();
    if (tid < 64) {
      float s = sred[0][tid] + sred[1][tid] + sred[2][tid] + sred[3][tid] + pb2[0];
      int qq = q0 + tid;
      if (qq < Q) out[qq] = 1.f / (1.f + expf(-s));
    }
  }
}

extern "C" void kernel_launch(void* const* d_in, const int* in_sizes, int n_in,
                              void* d_out, int out_size, void* d_ws, size_t ws_size,
                              hipStream_t stream) {
  const int* adj_row = (const int*)d_in[0];
  const int* adj_col = (const int*)d_in[1];
  const int* edges = (const int*)d_in[2];
  const float* emb = (const float*)d_in[3];
  const float* W0 = (const float*)d_in[4];
  const float* b0 = (const float*)d_in[5];
  const float* W1 = (const float*)d_in[6];
  const float* b1 = (const float*)d_in[7];
  const float* W2 = (const float*)d_in[8];
  const float* b2 = (const float*)d_in[9];
  const float* P0 = (const float*)d_in[10];
  const float* pb0 = (const float*)d_in[11];
  const float* P1 = (const float*)d_in[12];
  const float* pb1 = (const float*)d_in[13];
  const float* P2 = (const float*)d_in[14];
  const float* pb2 = (const float*)d_in[15];
  float* out = (float*)d_out;

  int E = in_sizes[0];
  int Q = in_sizes[2] / 2;
  int N = in_sizes[3] / D;
  int Npad = ((N + 63) / 64) * 64;
  int Npad2 = ((N + 1023) / 1024) * 1024;
  int nb = Npad2 / 1024;

  char* p = (char*)d_ws;
  auto alloc = [&](size_t bytes) {
    char* r = p;
    p += (bytes + 255) & ~(size_t)255;
    return r;
  };
  int* cnt = (int*)alloc((size_t)Npad2 * 4);
  int* cursor = (int*)alloc((size_t)Npad2 * 4);
  int* offs = (int*)alloc((size_t)(Npad2 + 1) * 4);
  float* dinv = (float*)alloc((size_t)Npad2 * 4);
  int* bsum = (int*)alloc((size_t)nb * 4);
  int2* csr = (int2*)alloc((size_t)E * 8);
  unsigned short* Wt = (unsigned short*)alloc((size_t)5 * 65536 * 2);
  unsigned short* XA = (unsigned short*)alloc((size_t)Npad * D * 2);
  unsigned int* XC8 = (unsigned int*)alloc((size_t)Npad * D);
  unsigned int* XA8 = (unsigned int*)XA;  // alias: XA(bf16) dead when layer-2 agg writes fp8

  hipMemsetAsync(cnt, 0, (size_t)Npad2 * 4, stream);
  hipMemsetAsync(cursor, 0, (size_t)Npad2 * 4, stream);

  int eb = (E + 255) / 256;
  k_count<<<eb, 256, 0, stream>>>(adj_row, cnt, E);
  k_scan1<<<nb, 256, 0, stream>>>(cnt, bsum);
  k_scan2<<<1, 256, 0, stream>>>(bsum, nb, offs + Npad2);
  k_scan3<<<nb, 256, 0, stream>>>(cnt, bsum, offs, dinv);
  k_scatter<<<eb, 256, 0, stream>>>(adj_row, adj_col, offs, cursor, dinv, csr, E);
  k_cast_w<<<5 * 64, 256, 0, stream>>>(W0, W1, W2, P0, P1, Wt);
  k_cast_emb<<<Npad / 4, 256, 0, stream>>>(emb, XA, N);

  const float* biases[3] = {b0, b1, b2};
  for (int l = 0; l < 3; ++l) {
    k_gemm<<<Npad / 64, 256, 0, stream>>>(XA, Wt + (size_t)l * 65536, XC8);
    k_agg<<<Npad / 16, 256, 0, stream>>>((const unsigned char*)XC8, dinv, offs, csr,
                                         biases[l], XA, XA8, (l < 2) ? 0 : 1);
  }
  k_lp<<<(Q + 63) / 64, 256, 0, stream>>>((const unsigned char*)XA8, edges, edges + Q,
                                          Wt + (size_t)3 * 65536, pb0,
                                          Wt + (size_t)4 * 65536, pb1, P2, pb2, out, Q);
}